// Round 7
// baseline (299.937 us; speedup 1.0000x reference)
//
#include <hip/hip_runtime.h>
#include <hip/hip_bf16.h>

// B=8, N=4096, C=384, H=8, HD=48.  M = B*N = 32768.
// Pipeline (4 kernels):
//  conv_w:    Wqkv,Wproj fp32->bf16; zero accD.
//  gemm_qkv:  x(fp32, converted in A-staging) @ Wqkv^T.
//             jobs 0-2: Q tile -> qp[tok][384] (activated bf16)
//             jobs 3-10 (head h): K+V 96-feat tile -> LDS transpose (union over As/Bs) ->
//                49x48 kptv/ks MFMA over 128 toks -> atomicAdd accD[bh][64][48]
//  attn_out:  qp x accD -> outr; denominator via v_rcp (not IEEE div)
//  gemm_proj: outr @ Wproj^T + bias -> fp32 out.

typedef __attribute__((ext_vector_type(8))) short short8;
typedef __attribute__((ext_vector_type(4))) float floatx4;

#define MFMA(a, b, c) __builtin_amdgcn_mfma_f32_16x16x32_bf16((a), (b), (c), 0, 0, 0)

// hardware v_cvt_pk_bf16_f32 via compiler intrinsic (m240: don't hand-write asm)
__device__ __forceinline__ unsigned pkbf(float a, float b) {
  __hip_bfloat162 h = __float22bfloat162_rn(make_float2(a, b));
  return *reinterpret_cast<unsigned*>(&h);
}
__device__ __forceinline__ unsigned short f2bf(float f) {
  __hip_bfloat16 h = __float2bfloat16(f);
  return *reinterpret_cast<unsigned short*>(&h);
}

__device__ __forceinline__ void cv4(const float* __restrict__ in, unsigned short* __restrict__ out, int i) {
  float4 v = *(const float4*)(in + i);
  uint2 o;
  o.x = pkbf(v.x, v.y);
  o.y = pkbf(v.z, v.w);
  *(uint2*)(out + i) = o;
}

// ---------------- weight conversions + accD zeroing ----------------
__global__ void conv_w(const float* __restrict__ wq, const float* __restrict__ wp,
                       unsigned short* __restrict__ wqb, unsigned short* __restrict__ wpb,
                       float* __restrict__ accD) {
  const int tid = blockIdx.x * blockDim.x + threadIdx.x;
  const int stride = gridDim.x * blockDim.x * 4;
  for (int i = tid * 4; i < 442368; i += stride) cv4(wq, wqb, i);
  for (int i = tid * 4; i < 147456; i += stride) cv4(wp, wpb, i);
  float4 z = {0.f, 0.f, 0.f, 0.f};
  for (int i = tid * 4; i < 196608; i += stride) *(float4*)(accD + i) = z;
}

// ---------------- fused qkv GEMM + kptv/ks reduction ----------------
// grid = 256 M-tiles * 11 jobs, XCD-swizzled so one tile's jobs share an L2.
__global__ __launch_bounds__(256, 2) void gemm_qkv(
    const float* __restrict__ x,            // [32768][384] fp32
    const unsigned short* __restrict__ Wq,  // [1152][384] bf16
    unsigned short* __restrict__ qp,        // [32768][384] bf16 out
    float* __restrict__ accD) {             // [64][64][48] fp32
  // Tt is only live after the K-loop's final barrier -> union over As/Bs (LDS 32 KB)
  __shared__ union {
    struct { unsigned short As[128 * 64]; unsigned short Bs[128 * 64]; } s;
    unsigned short Tt[2][48 * 136];
  } u;

  const int cpx = gridDim.x >> 3;
  const int bid = (blockIdx.x & 7) * cpx + (blockIdx.x >> 3);
  const int mt = bid / 11;
  const int j = bid - mt * 11;
  const int tid = threadIdx.x;
  const int w = tid >> 6, lane = tid & 63;
  const int wm = w >> 1, wn = w & 1;
  const int l15 = lane & 15, l4 = lane >> 4;
  const int isQ = (j < 3);
  const int h = j - 3;

  floatx4 zero = {0.f, 0.f, 0.f, 0.f};
  floatx4 acc[4][4];
#pragma unroll
  for (int i = 0; i < 4; ++i)
#pragma unroll
    for (int jj = 0; jj < 4; ++jj) acc[i][jj] = zero;

  const size_t Abase = (size_t)mt * 128 * 384;
  const int arow = tid >> 4;            // 0..15
  const int akf = (tid & 15) * 4;       // 0..60

  for (int k0 = 0; k0 < 384; k0 += 64) {
    // ---- A staging: x fp32 -> bf16 -> As[128][64] (reg-staged, HW cvt_pk) ----
#pragma unroll
    for (int p = 0; p < 8; ++p) {
      int row = p * 16 + arow;
      float4 v = *(const float4*)&x[Abase + (size_t)row * 384 + k0 + akf];
      uint2 o;
      o.x = pkbf(v.x, v.y);
      o.y = pkbf(v.z, v.w);
      *(uint2*)&u.s.As[row * 64 + akf] = o;
    }
    // ---- B staging ----
    if (isQ) {
      const size_t Bb = (size_t)(j * 128) * 384;
#pragma unroll
      for (int i = 0; i < 4; ++i) {
        int li = w * 256 + i * 64 + lane;
        int row = li >> 3, col = (li & 7) << 3;
        __builtin_amdgcn_global_load_lds(
            (const __attribute__((address_space(1))) void*)(Wq + Bb + (size_t)row * 384 + k0 + col),
            (__attribute__((address_space(3))) void*)&u.s.Bs[row * 64 + col], 16, 0, 0);
      }
    } else {
#pragma unroll
      for (int i = 0; i < 3; ++i) {
        int idx = i * 256 + tid;
        int row = idx >> 3, col = (idx & 7) << 3;
        int srow = (row < 48) ? (384 + h * 48 + row) : (720 + h * 48 + row);
        __builtin_amdgcn_global_load_lds(
            (const __attribute__((address_space(1))) void*)(Wq + (size_t)srow * 384 + k0 + col),
            (__attribute__((address_space(3))) void*)&u.s.Bs[row * 64 + col], 16, 0, 0);
      }
    }
    __syncthreads();
    // ---- MFMA ----
#pragma unroll
    for (int kk = 0; kk < 2; ++kk) {
      short8 a[4];
#pragma unroll
      for (int mf = 0; mf < 4; ++mf)
        a[mf] = *(const short8*)&u.s.As[(wm * 64 + mf * 16 + l15) * 64 + kk * 32 + l4 * 8];
      if (isQ) {
#pragma unroll
        for (int nf = 0; nf < 4; ++nf) {
          short8 b = *(const short8*)&u.s.Bs[(wn * 64 + nf * 16 + l15) * 64 + kk * 32 + l4 * 8];
#pragma unroll
          for (int mf = 0; mf < 4; ++mf) acc[mf][nf] = MFMA(a[mf], b, acc[mf][nf]);
        }
      } else {
#pragma unroll
        for (int nf = 0; nf < 3; ++nf) {
          short8 b = *(const short8*)&u.s.Bs[(wn * 48 + nf * 16 + l15) * 64 + kk * 32 + l4 * 8];
#pragma unroll
          for (int mf = 0; mf < 4; ++mf) acc[mf][nf] = MFMA(a[mf], b, acc[mf][nf]);
        }
      }
    }
    __syncthreads();
  }

  const float DN = 0.3799178430f;  // 48^-0.25
  if (isQ) {
    // Q tile -> qp[tok][384], activated
#pragma unroll
    for (int mf = 0; mf < 4; ++mf) {
#pragma unroll
      for (int nf = 0; nf < 4; ++nf) {
        int gm0 = mt * 128 + wm * 64 + mf * 16 + l4 * 4;
        int gn = j * 128 + wn * 64 + nf * 16 + l15;
#pragma unroll
        for (int r = 0; r < 4; ++r) {
          float v = fmaxf(acc[mf][nf][r] * DN, 0.f) + 1e-3f;
          qp[(size_t)(gm0 + r) * 384 + gn] = f2bf(v);
        }
      }
    }
  } else {
    // ---- transpose K (activated) / V (raw) into LDS: Tt[wn][feat][tok], packed 8B writes ----
    // (safe: final K-loop barrier has retired all As/Bs reads)
#pragma unroll
    for (int nf = 0; nf < 3; ++nf) {
#pragma unroll
      for (int mf = 0; mf < 4; ++mf) {
        float v0 = acc[mf][nf][0], v1 = acc[mf][nf][1];
        float v2 = acc[mf][nf][2], v3 = acc[mf][nf][3];
        if (wn == 0) {
          v0 = fmaxf(v0 * DN, 0.f) + 1e-3f;
          v1 = fmaxf(v1 * DN, 0.f) + 1e-3f;
          v2 = fmaxf(v2 * DN, 0.f) + 1e-3f;
          v3 = fmaxf(v3 * DN, 0.f) + 1e-3f;
        }
        uint2 o;
        o.x = pkbf(v0, v1);
        o.y = pkbf(v2, v3);
        *(uint2*)&u.Tt[wn][(nf * 16 + l15) * 136 + wm * 64 + mf * 16 + l4 * 4] = o;
      }
    }
    __syncthreads();
    // ---- second stage: out[d][m] = sum_tok V[tok][d]*Kp[tok][m]; wave3 row 0 = ks ----
    short8 ones;
    {
      unsigned short ov = (l15 == 0) ? (unsigned short)0x3F80 : (unsigned short)0;
#pragma unroll
      for (int e = 0; e < 8; ++e) ones[e] = (short)ov;
    }
    floatx4 acc2[3];
#pragma unroll
    for (int i = 0; i < 3; ++i) acc2[i] = zero;
#pragma unroll
    for (int c = 0; c < 4; ++c) {
      short8 af;
      if (w < 3)
        af = *(const short8*)&u.Tt[1][(w * 16 + l15) * 136 + c * 32 + l4 * 8];
      else
        af = ones;
#pragma unroll
      for (int mfr = 0; mfr < 3; ++mfr) {
        short8 bf8 = *(const short8*)&u.Tt[0][(mfr * 16 + l15) * 136 + c * 32 + l4 * 8];
        acc2[mfr] = MFMA(af, bf8, acc2[mfr]);
      }
    }
    float* dst = accD + (size_t)((mt >> 5) * 8 + h) * 3072;
    if (w < 3) {
#pragma unroll
      for (int mfr = 0; mfr < 3; ++mfr)
#pragma unroll
        for (int r = 0; r < 4; ++r)
          atomicAdd(&dst[(w * 16 + l4 * 4 + r) * 48 + mfr * 16 + l15], acc2[mfr][r]);
    } else if (l4 == 0) {
#pragma unroll
      for (int mfr = 0; mfr < 3; ++mfr)
        atomicAdd(&dst[48 * 48 + mfr * 16 + l15], acc2[mfr][0]);
    }
  }
}

// ---------------- out[n,d] = (qp[n,:] . kptv[d,:]) * rcp(qp[n,:] . ks + eps) ----------------
// kptv fragments loaded directly from fp32 accD.
// written in scrambled layout: outr[b, h*512 + n/8, (n%8)*48 + d]
__global__ __launch_bounds__(256, 2) void attn_out(
    const unsigned short* __restrict__ qp,   // [32768][384] activated Q
    const float* __restrict__ accD,
    unsigned short* __restrict__ outr) {
  const int bh = blockIdx.x >> 4, tg = blockIdx.x & 15;
  const int b = bh >> 3, h = bh & 7;
  const int tid = threadIdx.x, w = tid >> 6, lane = tid & 63;
  const int l15 = lane & 15, l4 = lane >> 4;
  const int t0 = tg * 256 + w * 64;

  // B-fragments: row = d (0..47 = kptv, 48 = ks), col = kernel-feature index m.
  short8 bfr[2][4];
#pragma unroll
  for (int kk = 0; kk < 2; ++kk) {
#pragma unroll
    for (int nf = 0; nf < 4; ++nf) {
      int row = nf * 16 + l15;
      int c0 = kk * 32 + l4 * 8;
      short8 f;
      if (kk == 1 && l4 >= 2) {
#pragma unroll
        for (int e = 0; e < 8; ++e) f[e] = 0;
      } else {
        const float* p = accD + (size_t)bh * 3072 + row * 48 + c0;
        float4 v0 = *(const float4*)p;
        float4 v1 = *(const float4*)(p + 4);
        unsigned* fu = (unsigned*)&f;
        fu[0] = pkbf(v0.x, v0.y);
        fu[1] = pkbf(v0.z, v0.w);
        fu[2] = pkbf(v1.x, v1.y);
        fu[3] = pkbf(v1.z, v1.w);
      }
      bfr[kk][nf] = f;
    }
  }

  floatx4 zero = {0.f, 0.f, 0.f, 0.f};
  floatx4 acc[4][4];
#pragma unroll
  for (int i = 0; i < 4; ++i)
#pragma unroll
    for (int j = 0; j < 4; ++j) acc[i][j] = zero;

  const size_t rb = (size_t)b * 4096;
#pragma unroll
  for (int mf = 0; mf < 4; ++mf) {
#pragma unroll
    for (int kk = 0; kk < 2; ++kk) {
      int tt = t0 + mf * 16 + l15;
      short8 a = *(const short8*)&qp[(rb + tt) * 384 + h * 48 + kk * 32 + l4 * 8];
#pragma unroll
      for (int nf = 0; nf < 4; ++nf)
        acc[mf][nf] = MFMA(a, bfr[kk][nf], acc[mf][nf]);
    }
  }

#pragma unroll
  for (int mf = 0; mf < 4; ++mf) {
    float inv[4];
#pragma unroll
    for (int r = 0; r < 4; ++r) {
      float den = __shfl(acc[mf][3][r], lane & 48, 64) + 1e-8f;
      inv[r] = __builtin_amdgcn_rcpf(den);  // 1-ulp rcp; output is bf16 anyway
    }
#pragma unroll
    for (int nf = 0; nf < 3; ++nf) {
#pragma unroll
      for (int r = 0; r < 4; ++r) {
        int tt = t0 + mf * 16 + l4 * 4 + r;
        int d = nf * 16 + l15;
        float v = acc[mf][nf][r] * inv[r];
        int np = h * 512 + (tt >> 3);
        int cp = (tt & 7) * 48 + d;
        outr[(rb + np) * 384 + cp] = f2bf(v);
      }
    }
  }
}

// ---------------- proj GEMM: outr(bf16) @ Wproj^T + bias -> fp32 ----------------
__global__ __launch_bounds__(256, 2) void gemm_proj(
    const unsigned short* __restrict__ A,   // [32768][384] bf16
    const unsigned short* __restrict__ Bt,  // [384][384] bf16
    float* __restrict__ Cout,
    const float* __restrict__ bias) {
  __shared__ unsigned short As[128 * 64];
  __shared__ unsigned short Bs[128 * 64];
  const int NT = 3;
  const int cpx = gridDim.x >> 3;
  const int bid = (blockIdx.x & 7) * cpx + (blockIdx.x >> 3);
  const int bn = bid % NT;
  const int bm = bid / NT;
  const int tid = threadIdx.x;
  const int w = tid >> 6, lane = tid & 63;
  const int wm = w >> 1, wn = w & 1;
  const int l15 = lane & 15, l4 = lane >> 4;

  floatx4 zero = {0.f, 0.f, 0.f, 0.f};
  floatx4 acc[4][4];
#pragma unroll
  for (int i = 0; i < 4; ++i)
#pragma unroll
    for (int j = 0; j < 4; ++j) acc[i][j] = zero;

  const int li0 = (w * 4) * 64 + lane;
  const size_t Abase = (size_t)(bm * 128) * 384;
  const size_t Bbase = (size_t)(bn * 128) * 384;

  for (int k0 = 0; k0 < 384; k0 += 64) {
#pragma unroll
    for (int i = 0; i < 4; ++i) {
      int li = li0 + i * 64;
      int row = li >> 3;
      int col = (li & 7) << 3;
      __builtin_amdgcn_global_load_lds(
          (const __attribute__((address_space(1))) void*)(A + Abase + (size_t)row * 384 + k0 + col),
          (__attribute__((address_space(3))) void*)&As[(w * 4 + i) * 512], 16, 0, 0);
      __builtin_amdgcn_global_load_lds(
          (const __attribute__((address_space(1))) void*)(Bt + Bbase + (size_t)row * 384 + k0 + col),
          (__attribute__((address_space(3))) void*)&Bs[(w * 4 + i) * 512], 16, 0, 0);
    }
    __syncthreads();
#pragma unroll
    for (int kk = 0; kk < 2; ++kk) {
      short8 a[4], b[4];
#pragma unroll
      for (int mf = 0; mf < 4; ++mf)
        a[mf] = *(const short8*)&As[(wm * 64 + mf * 16 + l15) * 64 + kk * 32 + l4 * 8];
#pragma unroll
      for (int nf = 0; nf < 4; ++nf)
        b[nf] = *(const short8*)&Bs[(wn * 64 + nf * 16 + l15) * 64 + kk * 32 + l4 * 8];
#pragma unroll
      for (int mf = 0; mf < 4; ++mf)
#pragma unroll
        for (int nf = 0; nf < 4; ++nf)
          acc[mf][nf] = MFMA(a[mf], b[nf], acc[mf][nf]);
    }
    __syncthreads();
  }

#pragma unroll
  for (int mf = 0; mf < 4; ++mf) {
#pragma unroll
    for (int nf = 0; nf < 4; ++nf) {
      int gm0 = bm * 128 + wm * 64 + mf * 16 + l4 * 4;
      int gn = bn * 128 + wn * 64 + nf * 16 + l15;
#pragma unroll
      for (int r = 0; r < 4; ++r)
        Cout[(size_t)(gm0 + r) * 384 + gn] = acc[mf][nf][r] + bias[gn];
    }
  }
}

extern "C" void kernel_launch(void* const* d_in, const int* in_sizes, int n_in,
                              void* d_out, int out_size, void* d_ws, size_t ws_size,
                              hipStream_t stream) {
  const float* x = (const float*)d_in[0];
  const float* Wqkv = (const float*)d_in[1];
  const float* Wproj = (const float*)d_in[2];
  const float* bproj = (const float*)d_in[3];

  char* ws = (char*)d_ws;
  unsigned short* qp = (unsigned short*)(ws);                 // 25165824
  float* accD = (float*)(ws + 25165824);                      // 786432
  unsigned short* outr = (unsigned short*)(ws + 25952256);    // 25165824
  unsigned short* wqkvb = (unsigned short*)(ws + 51118080);   // 884736
  unsigned short* wprojb = (unsigned short*)(ws + 52002816);  // 294912
  // total ws use: 52297728 bytes

  conv_w<<<256, 256, 0, stream>>>(Wqkv, Wproj, wqkvb, wprojb, accD);
  gemm_qkv<<<2816, 256, 0, stream>>>(x, wqkvb, qp, accD);
  attn_out<<<1024, 256, 0, stream>>>(qp, accD, outr);
  gemm_proj<<<768, 256, 0, stream>>>(outr, wprojb, (float*)d_out, bproj);
}

// Round 8
// 195.751 us; speedup vs baseline: 1.5322x; 1.5322x over previous
//
#include <hip/hip_runtime.h>
#include <hip/hip_bf16.h>

// B=8, N=4096, C=384, H=8, HD=48.  M = B*N = 32768.
// Pipeline (4 kernels):
//  conv_w:    Wqkv,Wproj fp32->bf16; zero accD.
//  gemm_qkv:  x(fp32, converted in A-staging, T14-prefetched) @ Wqkv^T.
//             jobs 0-2: Q tile -> qp[tok][384] (activated bf16)
//             jobs 3-10 (head h): K+V 96-feat tile -> LDS transpose ->
//                49x48 kptv/ks MFMA over 128 toks -> atomicAdd accD[bh][64][48]
//             NOTE: Tt must NOT be unioned with As/Bs — aliasing a
//             global_load_lds destination serializes staging (r7: 2x slowdown).
//  attn_out:  qp staged via LDS (104B-padded rows), x accD -> outr (scrambled layout)
//  gemm_proj: outr @ Wproj^T + bias -> fp32 out.

typedef __attribute__((ext_vector_type(8))) short short8;
typedef __attribute__((ext_vector_type(4))) float floatx4;

#define MFMA(a, b, c) __builtin_amdgcn_mfma_f32_16x16x32_bf16((a), (b), (c), 0, 0, 0)

__device__ __forceinline__ unsigned short f2bf(float f) {
  union { float f; unsigned u; } x; x.f = f;
  unsigned r = x.u + 0x7FFFu + ((x.u >> 16) & 1u);   // RNE
  return (unsigned short)(r >> 16);
}

__device__ __forceinline__ void cv4(const float* __restrict__ in, unsigned short* __restrict__ out, int i) {
  float4 v = *(const float4*)(in + i);
  uint2 o;
  o.x = (unsigned)f2bf(v.x) | ((unsigned)f2bf(v.y) << 16);
  o.y = (unsigned)f2bf(v.z) | ((unsigned)f2bf(v.w) << 16);
  *(uint2*)(out + i) = o;
}

// ---------------- weight conversions + accD zeroing ----------------
__global__ void conv_w(const float* __restrict__ wq, const float* __restrict__ wp,
                       unsigned short* __restrict__ wqb, unsigned short* __restrict__ wpb,
                       float* __restrict__ accD) {
  const int tid = blockIdx.x * blockDim.x + threadIdx.x;
  const int stride = gridDim.x * blockDim.x * 4;
  for (int i = tid * 4; i < 442368; i += stride) cv4(wq, wqb, i);
  for (int i = tid * 4; i < 147456; i += stride) cv4(wp, wpb, i);
  float4 z = {0.f, 0.f, 0.f, 0.f};
  for (int i = tid * 4; i < 196608; i += stride) *(float4*)(accD + i) = z;
}

// ---------------- fused qkv GEMM + kptv/ks reduction ----------------
// grid = 256 M-tiles * 11 jobs, XCD-swizzled so one tile's jobs share an L2.
__global__ __launch_bounds__(256, 2) void gemm_qkv(
    const float* __restrict__ x,            // [32768][384] fp32
    const unsigned short* __restrict__ Wq,  // [1152][384] bf16
    unsigned short* __restrict__ qp,        // [32768][384] bf16 out
    float* __restrict__ accD) {             // [64][64][48] fp32
  __shared__ unsigned short As[128 * 64];
  __shared__ unsigned short Bs[128 * 64];
  __shared__ unsigned short Tt[2][48 * 136];  // separate from As/Bs (see header note)

  const int cpx = gridDim.x >> 3;
  const int bid = (blockIdx.x & 7) * cpx + (blockIdx.x >> 3);
  const int mt = bid / 11;
  const int j = bid - mt * 11;
  const int tid = threadIdx.x;
  const int w = tid >> 6, lane = tid & 63;
  const int wm = w >> 1, wn = w & 1;
  const int l15 = lane & 15, l4 = lane >> 4;
  const int isQ = (j < 3);
  const int h = j - 3;

  floatx4 zero = {0.f, 0.f, 0.f, 0.f};
  floatx4 acc[4][4];
#pragma unroll
  for (int i = 0; i < 4; ++i)
#pragma unroll
    for (int jj = 0; jj < 4; ++jj) acc[i][jj] = zero;

  const size_t Abase = (size_t)mt * 128 * 384;
  const int arow = tid >> 4;            // 0..15
  const int akf = (tid & 15) * 4;       // 0..60

  // T14 prologue: prefetch x for k0=0 into regs
  float4 xv[8];
#pragma unroll
  for (int p = 0; p < 8; ++p)
    xv[p] = *(const float4*)&x[Abase + (size_t)(p * 16 + arow) * 384 + akf];

  for (int k0 = 0; k0 < 384; k0 += 64) {
    // ---- B staging first (async global_load_lds, latency overlaps A cvt/ds_write) ----
    if (isQ) {
      const size_t Bb = (size_t)(j * 128) * 384;
#pragma unroll
      for (int i = 0; i < 4; ++i) {
        int li = w * 256 + i * 64 + lane;
        int row = li >> 3, col = (li & 7) << 3;
        __builtin_amdgcn_global_load_lds(
            (const __attribute__((address_space(1))) void*)(Wq + Bb + (size_t)row * 384 + k0 + col),
            (__attribute__((address_space(3))) void*)&Bs[row * 64 + col], 16, 0, 0);
      }
    } else {
#pragma unroll
      for (int i = 0; i < 3; ++i) {
        int idx = i * 256 + tid;
        int row = idx >> 3, col = (idx & 7) << 3;
        int srow = (row < 48) ? (384 + h * 48 + row) : (720 + h * 48 + row);
        __builtin_amdgcn_global_load_lds(
            (const __attribute__((address_space(1))) void*)(Wq + (size_t)srow * 384 + k0 + col),
            (__attribute__((address_space(3))) void*)&Bs[row * 64 + col], 16, 0, 0);
      }
    }
    // ---- A: cvt prefetched regs -> As ----
#pragma unroll
    for (int p = 0; p < 8; ++p) {
      int row = p * 16 + arow;
      uint2 o;
      o.x = (unsigned)f2bf(xv[p].x) | ((unsigned)f2bf(xv[p].y) << 16);
      o.y = (unsigned)f2bf(xv[p].z) | ((unsigned)f2bf(xv[p].w) << 16);
      *(uint2*)&As[row * 64 + akf] = o;
    }
    __syncthreads();
    // ---- T14: issue next k-step's x loads BEFORE the MFMA phase ----
    if (k0 < 320) {
#pragma unroll
      for (int p = 0; p < 8; ++p)
        xv[p] = *(const float4*)&x[Abase + (size_t)(p * 16 + arow) * 384 + k0 + 64 + akf];
    }
    // ---- MFMA ----
#pragma unroll
    for (int kk = 0; kk < 2; ++kk) {
      short8 a[4];
#pragma unroll
      for (int mf = 0; mf < 4; ++mf)
        a[mf] = *(const short8*)&As[(wm * 64 + mf * 16 + l15) * 64 + kk * 32 + l4 * 8];
      if (isQ) {
#pragma unroll
        for (int nf = 0; nf < 4; ++nf) {
          short8 b = *(const short8*)&Bs[(wn * 64 + nf * 16 + l15) * 64 + kk * 32 + l4 * 8];
#pragma unroll
          for (int mf = 0; mf < 4; ++mf) acc[mf][nf] = MFMA(a[mf], b, acc[mf][nf]);
        }
      } else {
#pragma unroll
        for (int nf = 0; nf < 3; ++nf) {
          short8 b = *(const short8*)&Bs[(wn * 48 + nf * 16 + l15) * 64 + kk * 32 + l4 * 8];
#pragma unroll
          for (int mf = 0; mf < 4; ++mf) acc[mf][nf] = MFMA(a[mf], b, acc[mf][nf]);
        }
      }
    }
    __syncthreads();
  }

  const float DN = 0.3799178430f;  // 48^-0.25
  if (isQ) {
    // Q tile -> qp[tok][384], activated
#pragma unroll
    for (int mf = 0; mf < 4; ++mf) {
#pragma unroll
      for (int nf = 0; nf < 4; ++nf) {
        int gm0 = mt * 128 + wm * 64 + mf * 16 + l4 * 4;
        int gn = j * 128 + wn * 64 + nf * 16 + l15;
#pragma unroll
        for (int r = 0; r < 4; ++r) {
          float v = fmaxf(acc[mf][nf][r] * DN, 0.f) + 1e-3f;
          qp[(size_t)(gm0 + r) * 384 + gn] = f2bf(v);
        }
      }
    }
  } else {
    // ---- transpose K (activated) / V (raw) into LDS: Tt[wn][feat][tok] ----
#pragma unroll
    for (int nf = 0; nf < 3; ++nf) {
#pragma unroll
      for (int mf = 0; mf < 4; ++mf) {
        float v0 = acc[mf][nf][0], v1 = acc[mf][nf][1];
        float v2 = acc[mf][nf][2], v3 = acc[mf][nf][3];
        if (wn == 0) {
          v0 = fmaxf(v0 * DN, 0.f) + 1e-3f;
          v1 = fmaxf(v1 * DN, 0.f) + 1e-3f;
          v2 = fmaxf(v2 * DN, 0.f) + 1e-3f;
          v3 = fmaxf(v3 * DN, 0.f) + 1e-3f;
        }
        uint2 o;
        o.x = (unsigned)f2bf(v0) | ((unsigned)f2bf(v1) << 16);
        o.y = (unsigned)f2bf(v2) | ((unsigned)f2bf(v3) << 16);
        *(uint2*)&Tt[wn][(nf * 16 + l15) * 136 + wm * 64 + mf * 16 + l4 * 4] = o;
      }
    }
    __syncthreads();
    // ---- second stage: out[d][m] = sum_tok V[tok][d]*Kp[tok][m]; wave3 row 0 = ks ----
    short8 ones;
    {
      unsigned short ov = (l15 == 0) ? (unsigned short)0x3F80 : (unsigned short)0;
#pragma unroll
      for (int e = 0; e < 8; ++e) ones[e] = (short)ov;
    }
    floatx4 acc2[3];
#pragma unroll
    for (int i = 0; i < 3; ++i) acc2[i] = zero;
#pragma unroll
    for (int c = 0; c < 4; ++c) {
      short8 af;
      if (w < 3)
        af = *(const short8*)&Tt[1][(w * 16 + l15) * 136 + c * 32 + l4 * 8];
      else
        af = ones;
#pragma unroll
      for (int mfr = 0; mfr < 3; ++mfr) {
        short8 bf8 = *(const short8*)&Tt[0][(mfr * 16 + l15) * 136 + c * 32 + l4 * 8];
        acc2[mfr] = MFMA(af, bf8, acc2[mfr]);
      }
    }
    float* dst = accD + (size_t)((mt >> 5) * 8 + h) * 3072;
    if (w < 3) {
#pragma unroll
      for (int mfr = 0; mfr < 3; ++mfr)
#pragma unroll
        for (int r = 0; r < 4; ++r)
          atomicAdd(&dst[(w * 16 + l4 * 4 + r) * 48 + mfr * 16 + l15], acc2[mfr][r]);
    } else if (l4 == 0) {
#pragma unroll
      for (int mfr = 0; mfr < 3; ++mfr)
        atomicAdd(&dst[48 * 48 + mfr * 16 + l15], acc2[mfr][0]);
    }
  }
}

// ---------------- out[n,d] = (qp[n,:] . kptv[d,:]) * rcp(qp[n,:] . ks + eps) ----------------
// qp tile staged through LDS (coalesced 96B global runs; 104B-strided rows kill
// the 16-row uncoalesced A-fragment pattern).  kptv fragments from fp32 accD.
// written in scrambled layout: outr[b, h*512 + n/8, (n%8)*48 + d]
__global__ __launch_bounds__(256, 2) void attn_out(
    const unsigned short* __restrict__ qp,   // [32768][384] activated Q
    const float* __restrict__ accD,
    unsigned short* __restrict__ outr) {
  __shared__ unsigned short Qs[256 * 52 + 64];  // 256 tok x 48 feat, stride 52; +tail pad
  const int bh = blockIdx.x >> 4, tg = blockIdx.x & 15;
  const int b = bh >> 3, h = bh & 7;
  const int tid = threadIdx.x, w = tid >> 6, lane = tid & 63;
  const int l15 = lane & 15, l4 = lane >> 4;
  const int t0 = tg * 256 + w * 64;
  const size_t rb = (size_t)b * 4096;

  // B-fragments: row = d (0..47 = kptv, 48 = ks), col = kernel-feature index m.
  short8 bfr[2][4];
#pragma unroll
  for (int kk = 0; kk < 2; ++kk) {
#pragma unroll
    for (int nf = 0; nf < 4; ++nf) {
      int row = nf * 16 + l15;
      int c0 = kk * 32 + l4 * 8;
      short8 f;
      if (kk == 1 && l4 >= 2) {
#pragma unroll
        for (int e = 0; e < 8; ++e) f[e] = 0;
      } else {
        const float* p = accD + (size_t)bh * 3072 + row * 48 + c0;
        float4 v0 = *(const float4*)p;
        float4 v1 = *(const float4*)(p + 4);
        f[0] = (short)f2bf(v0.x); f[1] = (short)f2bf(v0.y);
        f[2] = (short)f2bf(v0.z); f[3] = (short)f2bf(v0.w);
        f[4] = (short)f2bf(v1.x); f[5] = (short)f2bf(v1.y);
        f[6] = (short)f2bf(v1.z); f[7] = (short)f2bf(v1.w);
      }
      bfr[kk][nf] = f;
    }
  }

  // ---- stage qp slice: 1536 16B chunks, idx = row*6 + part (coalesced) ----
#pragma unroll
  for (int c = 0; c < 6; ++c) {
    int idx = c * 256 + tid;
    int row = idx / 6;
    int part = idx - row * 6;
    short8 v = *(const short8*)&qp[(rb + tg * 256 + row) * 384 + h * 48 + part * 8];
    *(short8*)&Qs[row * 52 + part * 8] = v;
  }
  // zero the pads (cols 48..51 of each row + 64-short tail) so garbage x 0 != NaN
  *(uint2*)&Qs[tid * 52 + 48] = (uint2){0u, 0u};
  if (tid < 64) Qs[256 * 52 + tid] = 0;
  __syncthreads();

  floatx4 zero = {0.f, 0.f, 0.f, 0.f};
  floatx4 acc[4][4];
#pragma unroll
  for (int i = 0; i < 4; ++i)
#pragma unroll
    for (int j = 0; j < 4; ++j) acc[i][j] = zero;

#pragma unroll
  for (int mf = 0; mf < 4; ++mf) {
#pragma unroll
    for (int kk = 0; kk < 2; ++kk) {
      short8 a = *(const short8*)&Qs[(w * 64 + mf * 16 + l15) * 52 + kk * 32 + l4 * 8];
#pragma unroll
      for (int nf = 0; nf < 4; ++nf)
        acc[mf][nf] = MFMA(a, bfr[kk][nf], acc[mf][nf]);
    }
  }

#pragma unroll
  for (int mf = 0; mf < 4; ++mf) {
    float inv[4];
#pragma unroll
    for (int r = 0; r < 4; ++r) {
      float den = __shfl(acc[mf][3][r], lane & 48, 64) + 1e-8f;
      inv[r] = __builtin_amdgcn_rcpf(den);  // 1-ulp rcp; output is bf16 anyway
    }
#pragma unroll
    for (int nf = 0; nf < 3; ++nf) {
#pragma unroll
      for (int r = 0; r < 4; ++r) {
        int tt = t0 + mf * 16 + l4 * 4 + r;
        int d = nf * 16 + l15;
        float v = acc[mf][nf][r] * inv[r];
        int np = h * 512 + (tt >> 3);
        int cp = (tt & 7) * 48 + d;
        outr[(rb + np) * 384 + cp] = f2bf(v);
      }
    }
  }
}

// ---------------- proj GEMM: outr(bf16) @ Wproj^T + bias -> fp32 ----------------
__global__ __launch_bounds__(256, 2) void gemm_proj(
    const unsigned short* __restrict__ A,   // [32768][384] bf16
    const unsigned short* __restrict__ Bt,  // [384][384] bf16
    float* __restrict__ Cout,
    const float* __restrict__ bias) {
  __shared__ unsigned short As[128 * 64];
  __shared__ unsigned short Bs[128 * 64];
  const int NT = 3;
  const int cpx = gridDim.x >> 3;
  const int bid = (blockIdx.x & 7) * cpx + (blockIdx.x >> 3);
  const int bn = bid % NT;
  const int bm = bid / NT;
  const int tid = threadIdx.x;
  const int w = tid >> 6, lane = tid & 63;
  const int wm = w >> 1, wn = w & 1;
  const int l15 = lane & 15, l4 = lane >> 4;

  floatx4 zero = {0.f, 0.f, 0.f, 0.f};
  floatx4 acc[4][4];
#pragma unroll
  for (int i = 0; i < 4; ++i)
#pragma unroll
    for (int j = 0; j < 4; ++j) acc[i][j] = zero;

  const int li0 = (w * 4) * 64 + lane;
  const size_t Abase = (size_t)(bm * 128) * 384;
  const size_t Bbase = (size_t)(bn * 128) * 384;

  for (int k0 = 0; k0 < 384; k0 += 64) {
#pragma unroll
    for (int i = 0; i < 4; ++i) {
      int li = li0 + i * 64;
      int row = li >> 3;
      int col = (li & 7) << 3;
      __builtin_amdgcn_global_load_lds(
          (const __attribute__((address_space(1))) void*)(A + Abase + (size_t)row * 384 + k0 + col),
          (__attribute__((address_space(3))) void*)&As[(w * 4 + i) * 512], 16, 0, 0);
      __builtin_amdgcn_global_load_lds(
          (const __attribute__((address_space(1))) void*)(Bt + Bbase + (size_t)row * 384 + k0 + col),
          (__attribute__((address_space(3))) void*)&Bs[(w * 4 + i) * 512], 16, 0, 0);
    }
    __syncthreads();
#pragma unroll
    for (int kk = 0; kk < 2; ++kk) {
      short8 a[4], b[4];
#pragma unroll
      for (int mf = 0; mf < 4; ++mf)
        a[mf] = *(const short8*)&As[(wm * 64 + mf * 16 + l15) * 64 + kk * 32 + l4 * 8];
#pragma unroll
      for (int nf = 0; nf < 4; ++nf)
        b[nf] = *(const short8*)&Bs[(wn * 64 + nf * 16 + l15) * 64 + kk * 32 + l4 * 8];
#pragma unroll
      for (int mf = 0; mf < 4; ++mf)
#pragma unroll
        for (int nf = 0; nf < 4; ++nf)
          acc[mf][nf] = MFMA(a[mf], b[nf], acc[mf][nf]);
    }
    __syncthreads();
  }

#pragma unroll
  for (int mf = 0; mf < 4; ++mf) {
#pragma unroll
    for (int nf = 0; nf < 4; ++nf) {
      int gm0 = bm * 128 + wm * 64 + mf * 16 + l4 * 4;
      int gn = bn * 128 + wn * 64 + nf * 16 + l15;
#pragma unroll
      for (int r = 0; r < 4; ++r)
        Cout[(size_t)(gm0 + r) * 384 + gn] = acc[mf][nf][r] + bias[gn];
    }
  }
}

extern "C" void kernel_launch(void* const* d_in, const int* in_sizes, int n_in,
                              void* d_out, int out_size, void* d_ws, size_t ws_size,
                              hipStream_t stream) {
  const float* x = (const float*)d_in[0];
  const float* Wqkv = (const float*)d_in[1];
  const float* Wproj = (const float*)d_in[2];
  const float* bproj = (const float*)d_in[3];

  char* ws = (char*)d_ws;
  unsigned short* qp = (unsigned short*)(ws);                 // 25165824
  float* accD = (float*)(ws + 25165824);                      // 786432
  unsigned short* outr = (unsigned short*)(ws + 25952256);    // 25165824
  unsigned short* wqkvb = (unsigned short*)(ws + 51118080);   // 884736
  unsigned short* wprojb = (unsigned short*)(ws + 52002816);  // 294912
  // total ws use: 52297728 bytes

  conv_w<<<256, 256, 0, stream>>>(Wqkv, Wproj, wqkvb, wprojb, accD);
  gemm_qkv<<<2816, 256, 0, stream>>>(x, wqkvb, qp, accD);
  attn_out<<<1024, 256, 0, stream>>>(qp, accD, outr);
  gemm_proj<<<768, 256, 0, stream>>>(outr, wprojb, (float*)d_out, bproj);
}